// Round 6
// baseline (487.026 us; speedup 1.0000x reference)
//
#include <hip/hip_runtime.h>
#include <stdint.h>

#define D_DIM 256
#define NPAD  640   // 256 (W_lin) + 256 (W_res) + 8 (att_l) + 8 (att_r) + 112 zero pad -> 5 x 128 tiles

typedef __bf16 bf16x8 __attribute__((ext_vector_type(8)));
typedef float  f32x4  __attribute__((ext_vector_type(4)));

__device__ __forceinline__ float bf2f(unsigned short u) {
  union { unsigned int i; float f; } cv; cv.i = ((unsigned int)u) << 16; return cv.f;
}
__device__ __forceinline__ unsigned short f2bf(float f) {
  union { float f; unsigned int i; } cv; cv.f = f;
  unsigned int i = cv.i;
  unsigned int lsb = (i >> 16) & 1u;
  i += 0x7fffu + lsb;   // round-to-nearest-even
  return (unsigned short)(i >> 16);
}
__device__ __forceinline__ void gld16(const void* gptr, void* lptr) {
  __builtin_amdgcn_global_load_lds(
      (const __attribute__((address_space(1))) unsigned int*)gptr,
      (__attribute__((address_space(3))) unsigned int*)lptr, 16, 0, 0);
}

// ---------------- build Bt[n][k] (bf16) ----------------
__global__ __launch_bounds__(256) void prep_bt(
    const float* __restrict__ W_lin, const float* __restrict__ W_res,
    const float* __restrict__ att_l, const float* __restrict__ att_r,
    unsigned short* __restrict__ Bt) {
  int idx = blockIdx.x * 256 + threadIdx.x;
  if (idx >= NPAD * D_DIM) return;
  int n = idx >> 8, k = idx & 255;
  float v = 0.f;
  if (n < 256) v = W_lin[k * 256 + n];
  else if (n < 512) v = W_res[k * 256 + (n - 256)];
  else if (n < 520) {
    int h = n - 512; float s = 0.f;
    #pragma unroll
    for (int c = 0; c < 32; ++c) s += W_lin[k * 256 + h * 32 + c] * att_l[h * 32 + c];
    v = s;
  } else if (n < 528) {
    int h = n - 520; float s = 0.f;
    #pragma unroll
    for (int c = 0; c < 32; ++c) s += W_lin[k * 256 + h * 32 + c] * att_r[h * 32 + c];
    v = s;
  }
  Bt[idx] = f2bf(v);
}

// ---------------- hist: counts + per-edge rank (runs FIRST, off the GEMM) ----------------
__global__ __launch_bounds__(256) void hist_kernel(const int* __restrict__ dst,
                                                   int* __restrict__ cnt,
                                                   int* __restrict__ rank, int E) {
  int base = blockIdx.x * 2048 + threadIdx.x;
  #pragma unroll
  for (int u = 0; u < 8; ++u) {
    int e = base + u * 256;
    if (e < E) rank[e] = atomicAdd(&cnt[dst[e]], 1);   // 8 independent RMWs in flight
  }
}

// ---------------- single-block scan (N=50k: each thread serial-scans ~49) ----------------
__global__ __launch_bounds__(1024) void scan_one(const int* __restrict__ cnt,
                                                 int* __restrict__ row_ptr, int N) {
  __shared__ int sdata[1024];
  int t = threadIdx.x;
  int chunk = (N + 1023) >> 10;
  int b = t * chunk;
  int e = min(b + chunk, N);
  int s = 0;
  for (int i = b; i < e; ++i) s += cnt[i];
  sdata[t] = s;
  __syncthreads();
  for (int off = 1; off < 1024; off <<= 1) {
    int v = (t >= off) ? sdata[t - off] : 0;
    __syncthreads();
    sdata[t] += v;
    __syncthreads();
  }
  int run = sdata[t] - s;  // exclusive prefix
  for (int i = b; i < e; ++i) { row_ptr[i] = run; run += cnt[i]; }
  if (t == 1023) row_ptr[N] = sdata[1023];
}

// ---------------- fused [scatter | bf16 MFMA GEMM] ----------------
// blocks [0, nb_scat): CSR scatter (latency-bound random 8B writes) — placed FIRST so
// they overlap the MFMA-heavy GEMM phase. blocks >= nb_scat: GEMM tiles.
// GEMM stages A directly from fp32 feat (in-register bf16 convert) — no cvt pass.
__global__ __launch_bounds__(256) void gemm_scatter(
    const float* __restrict__ A32,          // feat fp32 [M][256]
    const unsigned short* __restrict__ Bt,  // [640][256] bf16
    float* __restrict__ out, unsigned short* __restrict__ xbf,
    float* __restrict__ alpha_l, float* __restrict__ alpha_r, int M,
    const int* __restrict__ eidx, const float* __restrict__ ew,
    const int* __restrict__ row_ptr, const int* __restrict__ rank,
    int2* __restrict__ pairs, int E, int nb_scat, int gx) {
  __shared__ unsigned short As[128 * 32];
  __shared__ unsigned short Bs[128 * 32];

  if ((int)blockIdx.x < nb_scat) {
    int base = (int)blockIdx.x * 1024 + threadIdx.x;
    #pragma unroll
    for (int u = 0; u < 4; ++u) {
      int e = base + u * 256;
      if (e < E) {
        int d = eidx[E + e];
        int pos = row_ptr[d] + rank[e];
        int2 p; p.x = eidx[e]; p.y = __float_as_int(ew[e]);
        pairs[pos] = p;
      }
    }
    return;
  }

  int tid  = threadIdx.x;
  int w    = tid >> 6, lane = tid & 63;
  int gb   = (int)blockIdx.x - nb_scat;
  int bm   = (gb % gx) * 128, bn = (gb / gx) * 128;
  int wm   = (w & 1) * 64, wn = (w >> 1) * 64;
  int l16  = lane & 15, quad = lane >> 4;

  f32x4 acc[4][4] = {};

  int brow = w * 32 + (lane >> 2);   // B staging row (+ i*16)
  int bkoff = (lane & 3) * 8;        // B staging k offset (elements)

  for (int k0 = 0; k0 < 256; k0 += 32) {
    // stage A: 128 rows x 32 k, fp32 -> bf16 in-register, 8 elems/thread x 2 passes
    #pragma unroll
    for (int ps = 0; ps < 2; ++ps) {
      int idx = ps * 256 + tid;          // 0..511
      int r   = idx >> 2;                // 0..127
      int k8  = (idx & 3) * 8;
      int rg  = bm + r; if (rg > M - 1) rg = M - 1;   // clamp (stores guarded)
      const float* ap = A32 + (size_t)rg * 256 + k0 + k8;
      float4 u0 = *(const float4*)ap;
      float4 u1 = *(const float4*)(ap + 4);
      ushort4 c0, c1;
      c0.x = f2bf(u0.x); c0.y = f2bf(u0.y); c0.z = f2bf(u0.z); c0.w = f2bf(u0.w);
      c1.x = f2bf(u1.x); c1.y = f2bf(u1.y); c1.z = f2bf(u1.z); c1.w = f2bf(u1.w);
      *(ushort4*)&As[r * 32 + k8]     = c0;
      *(ushort4*)&As[r * 32 + k8 + 4] = c1;
    }
    // stage B via global_load_lds (bf16 source)
    #pragma unroll
    for (int i = 0; i < 2; ++i) {
      int r = brow + i * 16;
      gld16(Bt + (size_t)(bn + r) * 256 + k0 + bkoff, &Bs[(w * 32 + i * 16) * 32]);
    }
    __syncthreads();
    bf16x8 a[4], b[4];
    #pragma unroll
    for (int mi = 0; mi < 4; ++mi)
      a[mi] = *(const bf16x8*)&As[(wm + mi * 16 + l16) * 32 + quad * 8];
    #pragma unroll
    for (int ni = 0; ni < 4; ++ni)
      b[ni] = *(const bf16x8*)&Bs[(wn + ni * 16 + l16) * 32 + quad * 8];
    #pragma unroll
    for (int mi = 0; mi < 4; ++mi)
      #pragma unroll
      for (int ni = 0; ni < 4; ++ni)
        acc[mi][ni] = __builtin_amdgcn_mfma_f32_16x16x32_bf16(a[mi], b[ni], acc[mi][ni], 0, 0, 0);
    __syncthreads();
  }

  #pragma unroll
  for (int mi = 0; mi < 4; ++mi) {
    #pragma unroll
    for (int r = 0; r < 4; ++r) {
      int row = bm + wm + mi * 16 + quad * 4 + r;
      if (row >= M) continue;
      #pragma unroll
      for (int ni = 0; ni < 4; ++ni) {
        int n = bn + wn + ni * 16 + l16;
        float v = acc[mi][ni][r];
        if (n < 256)      xbf[(size_t)row * 256 + n] = f2bf(v);
        else if (n < 512) out[(size_t)row * 256 + (n - 256)] = v;
        else if (n < 520) alpha_l[row * 8 + (n - 512)] = v;
        else if (n < 528) alpha_r[row * 8 + (n - 520)] = v;
      }
    }
  }
}

// ---------------- one wave per dst node: direct-exp softmax + aggregation ----------------
// scores bounded (|a| <~ 16) -> exp without max-shift safe in fp32 -> commutative reduction
// -> unroll x4 (measured optimum: x8 gains nothing and costs occupancy).
__global__ __launch_bounds__(256) void agg_kernel(
    const int* __restrict__ row_ptr, const int2* __restrict__ pairs,
    const float* __restrict__ alpha_l, const float* __restrict__ alpha_r,
    const unsigned short* __restrict__ xbf, float* __restrict__ out, int N) {
  int node = blockIdx.x * 4 + (threadIdx.x >> 6);
  if (node >= N) return;
  int lane = threadIdx.x & 63;
  int h  = lane >> 3;     // head for this lane's 4 channels
  int cb = lane << 2;     // channel base (0..252)

  int beg = row_ptr[node], end = row_ptr[node + 1];
  float arv = alpha_r[node * 8 + h];
  float l = 0.f;
  float ac0 = 0.f, ac1 = 0.f, ac2 = 0.f, ac3 = 0.f;

  if (beg < end) {
    int last = end - 1;
    const unsigned short* xb = xbf + cb;
    for (int jg = beg; jg < end; jg += 4) {
      int2 q[4];
      #pragma unroll
      for (int u = 0; u < 4; ++u) {
        int t = jg + u; t = (t < last) ? t : last;   // clamped (masked below)
        q[u] = pairs[t];
      }
      float al[4];
      #pragma unroll
      for (int u = 0; u < 4; ++u) al[u] = alpha_l[(size_t)q[u].x * 8 + h];
      ushort4 xv[4];
      #pragma unroll
      for (int u = 0; u < 4; ++u)
        xv[u] = *(const ushort4*)(xb + ((size_t)q[u].x << 8));
      #pragma unroll
      for (int u = 0; u < 4; ++u) {
        float a = __int_as_float(q[u].y) * (al[u] + arv);
        a = (a > 0.f) ? a : 0.2f * a;            // leaky_relu(0.2)
        float p = __expf(a);
        p = (jg + u < end) ? p : 0.f;            // mask tail
        l += p;
        ac0 = fmaf(p, bf2f(xv[u].x), ac0);
        ac1 = fmaf(p, bf2f(xv[u].y), ac1);
        ac2 = fmaf(p, bf2f(xv[u].z), ac2);
        ac3 = fmaf(p, bf2f(xv[u].w), ac3);
      }
    }
  }
  float r = 1.0f / (l + 1e-16f);
  float o0 = ac0 * r, o1 = ac1 * r, o2 = ac2 * r, o3 = ac3 * r;
  o0 = (o0 > 0.f) ? o0 : expm1f(o0);  // elu
  o1 = (o1 > 0.f) ? o1 : expm1f(o1);
  o2 = (o2 > 0.f) ? o2 : expm1f(o2);
  o3 = (o3 > 0.f) ? o3 : expm1f(o3);
  float4* op = (float4*)(out + ((size_t)node << 8) + cb);
  float4 res = *op;                    // residual written by gemm epilogue
  res.x += o0; res.y += o1; res.z += o2; res.w += o3;
  *op = res;
}

extern "C" void kernel_launch(void* const* d_in, const int* in_sizes, int n_in,
                              void* d_out, int out_size, void* d_ws, size_t ws_size,
                              hipStream_t stream) {
  const float* feat  = (const float*)d_in[0];
  const float* ew    = (const float*)d_in[1];
  const float* W_lin = (const float*)d_in[2];
  const float* att_l = (const float*)d_in[3];
  const float* att_r = (const float*)d_in[4];
  const float* W_res = (const float*)d_in[5];
  const int*   eidx  = (const int*)d_in[6];
  float* out = (float*)d_out;

  int N = in_sizes[0] / D_DIM;
  int E = in_sizes[1];

  char* p = (char*)d_ws;
  auto alloc = [&](size_t bytes) {
    char* r = p; p += (bytes + 255) & ~(size_t)255; return r;
  };
  unsigned short* xbf  = (unsigned short*)alloc((size_t)N * 256 * 2);   // 25.6 MB
  float* alpha_l       = (float*)alloc((size_t)N * 8 * 4);
  float* alpha_r       = (float*)alloc((size_t)N * 8 * 4);
  unsigned short* Bt   = (unsigned short*)alloc((size_t)NPAD * D_DIM * 2);
  int*   row_ptr       = (int*)alloc((size_t)(N + 1) * 4);
  int*   cnt           = (int*)alloc((size_t)N * 4);
  int*   rank          = (int*)alloc((size_t)E * 4);
  int2*  pairs         = (int2*)alloc((size_t)E * 8);                   // total ~48.6 MB

  int nb_prep = NPAD * D_DIM / 256;
  int nb_hist = (E + 2047) / 2048;    // 8 edges/thread
  int nb_scat = (E + 1023) / 1024;    // 4 edges/thread
  int gx = (N + 127) / 128;
  int gemm_blocks = gx * (NPAD / 128);

  hipMemsetAsync(cnt, 0, (size_t)N * 4, stream);

  prep_bt<<<nb_prep, 256, 0, stream>>>(W_lin, W_res, att_l, att_r, Bt);

  hist_kernel<<<nb_hist, 256, 0, stream>>>(eidx + E, cnt, rank, E);

  scan_one<<<1, 1024, 0, stream>>>(cnt, row_ptr, N);

  gemm_scatter<<<nb_scat + gemm_blocks, 256, 0, stream>>>(
      feat, Bt, out, xbf, alpha_l, alpha_r, N,
      eidx, ew, row_ptr, rank, pairs, E, nb_scat, gx);

  agg_kernel<<<(N + 3) / 4, 256, 0, stream>>>(row_ptr, pairs, alpha_l, alpha_r, xbf, out, N);
}